// Round 1
// baseline (9381.065 us; speedup 1.0000x reference)
//
#include <hip/hip_runtime.h>

#define BB 128
#define TT 1024
#define INP 54
#define HUM 64
#define DECN 256
#define ENCN 256
#define KLAT 16
#define NPSI 96540
#define OFF_BH 65536
#define OFF_WIH 65792
#define OFF_C 79616
#define OFF_D 96000
#define OUT_MU 8388608
#define OUT_LS 8390656
#define OUT_HL 8392704

typedef unsigned int u32;
typedef _Float16 h2 __attribute__((ext_vector_type(2)));

__device__ __forceinline__ u32 pk(float a, float b) {
    h2 v; v.x = (_Float16)a; v.y = (_Float16)b;
    return __builtin_bit_cast(u32, v);
}

__device__ __forceinline__ float fd2(u32 a, u32 b, float c) {
#if __has_builtin(__builtin_amdgcn_fdot2)
    return __builtin_amdgcn_fdot2(__builtin_bit_cast(h2, a), __builtin_bit_cast(h2, b), c, false);
#else
    h2 ha = __builtin_bit_cast(h2, a), hb = __builtin_bit_cast(h2, b);
    return c + (float)ha.x * (float)hb.x + (float)ha.y * (float)hb.y;
#endif
}

__device__ __forceinline__ float fsig(float x) { return 1.f / (1.f + __expf(-x)); }
__device__ __forceinline__ float ftanh(float x) { float e = __expf(2.f * x); return 1.f - 2.f / (e + 1.f); }

#define RED2(v) { v += __shfl_xor(v, 1); v += __shfl_xor(v, 2); }

// ---------------------------------------------------------------- encoder ---
struct EncLds {
    u32 wih[4 * 768 * 9];   // seg-major f16 pairs, padded stride 9
    float brz[512];         // bih+bhh for r (0..255) and z (256..511)
    float bin[256];         // bih n-part
    float bhn[256];         // bhh n-part
    float hf[256];
    u32 hp[128];            // h packed f16 pairs
    u32 xp[2][32];          // x packed, padded to 64, double buffered
};

__global__ __launch_bounds__(512, 1) void enc_kernel(
    const float* __restrict__ inp, const float* __restrict__ Wih,
    const float* __restrict__ Whh, const float* __restrict__ bih,
    const float* __restrict__ bhh, float* __restrict__ henc)
{
    extern __shared__ char smem[];
    EncLds* S = (EncLds*)smem;
    const int tid = threadIdx.x;
    const int b = blockIdx.x;
    const int l = tid & 3;
    const int g = tid >> 2;       // 0..127
    const int j0 = 2 * g, j1 = 2 * g + 1;

    // recurrent weights -> registers (f16 pairs), segment l = h[64l..64l+63]
    u32 wr0[32], wz0[32], wn0[32], wr1[32], wz1[32], wn1[32];
    {
        const float* pr0 = Whh + (size_t)j0 * 256 + 64 * l;
        const float* pz0 = Whh + (size_t)(j0 + 256) * 256 + 64 * l;
        const float* pn0 = Whh + (size_t)(j0 + 512) * 256 + 64 * l;
        const float* pr1 = Whh + (size_t)j1 * 256 + 64 * l;
        const float* pz1 = Whh + (size_t)(j1 + 256) * 256 + 64 * l;
        const float* pn1 = Whh + (size_t)(j1 + 512) * 256 + 64 * l;
#pragma unroll
        for (int c = 0; c < 32; ++c) {
            wr0[c] = pk(pr0[2 * c], pr0[2 * c + 1]);
            wz0[c] = pk(pz0[2 * c], pz0[2 * c + 1]);
            wn0[c] = pk(pn0[2 * c], pn0[2 * c + 1]);
            wr1[c] = pk(pr1[2 * c], pr1[2 * c + 1]);
            wz1[c] = pk(pz1[2 * c], pz1[2 * c + 1]);
            wn1[c] = pk(pn1[2 * c], pn1[2 * c + 1]);
        }
    }
    // Wih -> LDS (seg-major, 16 cols per seg, padded with zeros)
    for (int ll = 0; ll < 4; ++ll)
        for (int idx = tid; idx < 768 * 8; idx += 512) {
            int row = idx >> 3, k = idx & 7;
            int c0 = ll * 16 + 2 * k;
            float a = (c0 < INP) ? Wih[row * INP + c0] : 0.f;
            float bv = (c0 + 1 < INP) ? Wih[row * INP + c0 + 1] : 0.f;
            S->wih[(ll * 768 + row) * 9 + k] = pk(a, bv);
        }
    if (tid < 256) {
        S->brz[tid] = bih[tid] + bhh[tid];
        S->brz[256 + tid] = bih[256 + tid] + bhh[256 + tid];
        S->bin[tid] = bih[512 + tid];
        S->bhn[tid] = bhh[512 + tid];
        S->hf[tid] = 0.f;
    }
    if (tid < 128) S->hp[tid] = 0u;
    if (tid < 32) {
        const size_t base = (size_t)b * TT * INP;
        int c = tid;
        float a = (2 * c < INP) ? inp[base + 2 * c] : 0.f;
        float bv = (2 * c + 1 < INP) ? inp[base + 2 * c + 1] : 0.f;
        S->xp[0][c] = pk(a, bv);
    }
    __syncthreads();

    for (int ts = 0; ts < TT; ++ts) {
        const int p = ts & 1;
        float ar0 = 0, az0 = 0, ai0 = 0, ah0 = 0, ar1 = 0, az1 = 0, ai1 = 0, ah1 = 0;
        u32 xq[8];
#pragma unroll
        for (int k = 0; k < 8; ++k) xq[k] = S->xp[p][l * 8 + k];
        // x-side (gi): rows j (r), 256+j (z), 512+j (n -> ai)
#pragma unroll
        for (int k = 0; k < 8; ++k) {
            ar0 = fd2(S->wih[(l * 768 + j0) * 9 + k], xq[k], ar0);
            az0 = fd2(S->wih[(l * 768 + 256 + j0) * 9 + k], xq[k], az0);
            ai0 = fd2(S->wih[(l * 768 + 512 + j0) * 9 + k], xq[k], ai0);
            ar1 = fd2(S->wih[(l * 768 + j1) * 9 + k], xq[k], ar1);
            az1 = fd2(S->wih[(l * 768 + 256 + j1) * 9 + k], xq[k], az1);
            ai1 = fd2(S->wih[(l * 768 + 512 + j1) * 9 + k], xq[k], ai1);
        }
        // h-side (gh) from register weights
        const uint4* hp4 = (const uint4*)S->hp;
#pragma unroll
        for (int cc = 0; cc < 8; ++cc) {
            uint4 q = hp4[l * 8 + cc];
            u32 qa[4] = {q.x, q.y, q.z, q.w};
#pragma unroll
            for (int u = 0; u < 4; ++u) {
                const int c = cc * 4 + u;
                ar0 = fd2(wr0[c], qa[u], ar0); ar1 = fd2(wr1[c], qa[u], ar1);
                az0 = fd2(wz0[c], qa[u], az0); az1 = fd2(wz1[c], qa[u], az1);
                ah0 = fd2(wn0[c], qa[u], ah0); ah1 = fd2(wn1[c], qa[u], ah1);
            }
        }
        RED2(ar0) RED2(ar1) RED2(az0) RED2(az1)
        RED2(ah0) RED2(ah1) RED2(ai0) RED2(ai1)
        __syncthreads();
        if (l < 2) {
            const int j = 2 * g + l;
            const float aR = (l == 0) ? ar0 : ar1, aZ = (l == 0) ? az0 : az1;
            const float aH = (l == 0) ? ah0 : ah1, aI = (l == 0) ? ai0 : ai1;
            float r = fsig(aR + S->brz[j]);
            float z = fsig(aZ + S->brz[256 + j]);
            float n = ftanh(aI + S->bin[j] + r * (aH + S->bhn[j]));
            float hn = (1.f - z) * n + z * S->hf[j];
            S->hf[j] = hn;
            float ho = __shfl_xor(hn, 1);
            if (l == 0) S->hp[g] = pk(hn, ho);
        } else if (l == 2 && g < 32 && ts + 1 < TT) {
            const int c = g;
            const size_t base = ((size_t)b * TT + ts + 1) * INP;
            float a = (2 * c < INP) ? inp[base + 2 * c] : 0.f;
            float bv = (2 * c + 1 < INP) ? inp[base + 2 * c + 1] : 0.f;
            S->xp[p ^ 1][c] = pk(a, bv);
        }
        __syncthreads();
    }
    if (tid < 256) henc[(size_t)b * 256 + tid] = S->hf[tid];
}

// ----------------------------------------------------------------- latent ---
__global__ __launch_bounds__(256) void latent_kernel(
    const float* __restrict__ henc, const float* __restrict__ eps,
    const float* __restrict__ to_mu, const float* __restrict__ to_ls,
    const float* __restrict__ W1, const float* __restrict__ b1,
    const float* __restrict__ W2, const float* __restrict__ b2,
    float* __restrict__ psi2, float* __restrict__ out)
{
    __shared__ float h[256], zz[16], p1[256];
    const int tid = threadIdx.x, b = blockIdx.x;
    h[tid] = henc[(size_t)b * 256 + tid];
    __syncthreads();
    if (tid < 16) {
        float m = 0, s = 0;
        for (int k = 0; k < 256; ++k) {
            m += h[k] * to_mu[tid * 256 + k];
            s += h[k] * to_ls[tid * 256 + k];
        }
        out[OUT_MU + b * 16 + tid] = m;
        out[OUT_LS + b * 16 + tid] = s;
        zz[tid] = m + eps[b * 16 + tid] * __expf(s);
    }
    __syncthreads();
    {
        float a = b1[tid];
        for (int k = 0; k < 16; ++k) a += zz[k] * W1[tid * 16 + k];
        p1[tid] = ftanh(a);
    }
    __syncthreads();
    if (tid < 32) {
        float a = b2[tid];
        for (int k = 0; k < 256; ++k) a += p1[k] * W2[tid * 256 + k];
        psi2[b * 32 + tid] = a;
    }
}

// ------------------------------------------------------------------- psi3 ---
__global__ __launch_bounds__(256) void psi3_kernel(
    const float* __restrict__ psi2, const float* __restrict__ W3,
    const float* __restrict__ b3, float* __restrict__ psi)
{
    __shared__ float sp2[128 * 32];
    __shared__ float w3t[256 * 33];
    const int tid = threadIdx.x;
    const int n0 = blockIdx.x * 256;
    for (int idx = tid; idx < 4096; idx += 256) sp2[idx] = psi2[idx];
    for (int idx = tid; idx < 8192; idx += 256) {
        int row = idx >> 5, k = idx & 31;
        int n = n0 + row;
        w3t[row * 33 + k] = (n < NPSI) ? W3[(size_t)n * 32 + k] : 0.f;
    }
    __syncthreads();
    const int n = n0 + tid;
    if (n < NPSI) {
        float w[32];
#pragma unroll
        for (int k = 0; k < 32; ++k) w[k] = w3t[tid * 33 + k];
        const float bv = b3[n];
        for (int bi = 0; bi < 128; ++bi) {
            float a = bv;
#pragma unroll
            for (int k = 0; k < 32; ++k) a += sp2[bi * 32 + k] * w[k];
            psi[(size_t)bi * NPSI + n] = a;
        }
    }
}

// ---------------------------------------------------------------- decoder ---
struct DecLds {
    u32 gwih[4 * 512 * 9];
    u32 wihp[4 * 256 * 9];
    u32 cp[128 * 64];       // [h-pair][o] f16 pairs of C_p columns
    float dp[544];
    float bh[256];
    float gz[256];
    float gr[256];
    float hf[256];
    u32 hp[128];
    u32 xp[2][32];
    float xf[2][64];
    float part[512];
};

__global__ __launch_bounds__(512, 1) void dec_kernel(
    const float* __restrict__ inp, const float* __restrict__ state,
    const float* __restrict__ gWih, const float* __restrict__ gWhh,
    const float* __restrict__ gbias, const float* __restrict__ psi,
    float* __restrict__ out)
{
    extern __shared__ char smem[];
    DecLds* S = (DecLds*)smem;
    const int tid = threadIdx.x;
    const int b = blockIdx.x;
    const int l = tid & 3;
    const int g = tid >> 2;
    const int j0 = 2 * g, j1 = 2 * g + 1;
    const float* psi_b = psi + (size_t)b * NPSI;

    // register weights: gru_Whh columns (z: j, r: 256+j) and Whh_p columns j
    u32 wz0[32], wr0[32], wp0[32], wz1[32], wr1[32], wp1[32];
#pragma unroll
    for (int c = 0; c < 32; ++c) {
        const int h0 = 64 * l + 2 * c;
        wz0[c] = pk(gWhh[(size_t)h0 * 512 + j0], gWhh[(size_t)(h0 + 1) * 512 + j0]);
        wr0[c] = pk(gWhh[(size_t)h0 * 512 + 256 + j0], gWhh[(size_t)(h0 + 1) * 512 + 256 + j0]);
        wp0[c] = pk(psi_b[(size_t)h0 * 256 + j0], psi_b[(size_t)(h0 + 1) * 256 + j0]);
        wz1[c] = pk(gWhh[(size_t)h0 * 512 + j1], gWhh[(size_t)(h0 + 1) * 512 + j1]);
        wr1[c] = pk(gWhh[(size_t)h0 * 512 + 256 + j1], gWhh[(size_t)(h0 + 1) * 512 + 256 + j1]);
        wp1[c] = pk(psi_b[(size_t)h0 * 256 + j1], psi_b[(size_t)(h0 + 1) * 256 + j1]);
    }
    for (int ll = 0; ll < 4; ++ll)
        for (int idx = tid; idx < 512 * 8; idx += 512) {
            int row = idx >> 3, k = idx & 7;
            int c0 = ll * 16 + 2 * k;
            float a = (c0 < INP) ? gWih[row * INP + c0] : 0.f;
            float bv = (c0 + 1 < INP) ? gWih[row * INP + c0 + 1] : 0.f;
            S->gwih[(ll * 512 + row) * 9 + k] = pk(a, bv);
        }
    for (int ll = 0; ll < 4; ++ll)
        for (int idx = tid; idx < 256 * 8; idx += 512) {
            int row = idx >> 3, k = idx & 7;
            int c0 = ll * 16 + 2 * k;
            float a = (c0 < INP) ? psi_b[OFF_WIH + row * INP + c0] : 0.f;
            float bv = (c0 + 1 < INP) ? psi_b[OFF_WIH + row * INP + c0 + 1] : 0.f;
            S->wihp[(ll * 256 + row) * 9 + k] = pk(a, bv);
        }
    for (int idx = tid; idx < 128 * 64; idx += 512) {
        int hpi = idx >> 6, o = idx & 63;
        S->cp[idx] = pk(psi_b[OFF_C + (size_t)(2 * hpi) * 64 + o],
                        psi_b[OFF_C + (size_t)(2 * hpi + 1) * 64 + o]);
    }
    for (int idx = tid; idx < 540; idx += 512) S->dp[idx] = psi_b[OFF_D + idx];
    if (tid < 256) {
        S->bh[tid] = psi_b[OFF_BH + tid];
        S->gz[tid] = gbias[tid];
        S->gr[tid] = gbias[256 + tid];
        S->hf[tid] = state[(size_t)b * 256 + tid];
    }
    if (tid < 128) S->hp[tid] = pk(state[(size_t)b * 256 + 2 * tid], state[(size_t)b * 256 + 2 * tid + 1]);
    if (tid < 32) {
        const size_t base = (size_t)b * TT * INP;
        int c = tid;
        float a = (2 * c < INP) ? inp[base + 2 * c] : 0.f;
        float bv = (2 * c + 1 < INP) ? inp[base + 2 * c + 1] : 0.f;
        S->xp[0][c] = pk(a, bv);
    }
    if (tid >= 64 && tid < 128) {
        const int c = tid - 64;
        S->xf[0][c] = (c < INP) ? inp[(size_t)b * TT * INP + c] : 0.f;
    }
    __syncthreads();

    for (int ts = 0; ts < TT; ++ts) {
        const int p = ts & 1;
        float az0 = 0, ar0 = 0, ap0 = 0, ax0 = 0, az1 = 0, ar1 = 0, ap1 = 0, ax1 = 0;
        u32 xq[8];
#pragma unroll
        for (int k = 0; k < 8; ++k) xq[k] = S->xp[p][l * 8 + k];
#pragma unroll
        for (int k = 0; k < 8; ++k) {
            az0 = fd2(S->gwih[(l * 512 + j0) * 9 + k], xq[k], az0);
            ar0 = fd2(S->gwih[(l * 512 + 256 + j0) * 9 + k], xq[k], ar0);
            ax0 = fd2(S->wihp[(l * 256 + j0) * 9 + k], xq[k], ax0);
            az1 = fd2(S->gwih[(l * 512 + j1) * 9 + k], xq[k], az1);
            ar1 = fd2(S->gwih[(l * 512 + 256 + j1) * 9 + k], xq[k], ar1);
            ax1 = fd2(S->wihp[(l * 256 + j1) * 9 + k], xq[k], ax1);
        }
        const uint4* hp4 = (const uint4*)S->hp;
#pragma unroll
        for (int cc = 0; cc < 8; ++cc) {
            uint4 q = hp4[l * 8 + cc];
            u32 qa[4] = {q.x, q.y, q.z, q.w};
#pragma unroll
            for (int u = 0; u < 4; ++u) {
                const int c = cc * 4 + u;
                az0 = fd2(wz0[c], qa[u], az0); az1 = fd2(wz1[c], qa[u], az1);
                ar0 = fd2(wr0[c], qa[u], ar0); ar1 = fd2(wr1[c], qa[u], ar1);
                ap0 = fd2(wp0[c], qa[u], ap0); ap1 = fd2(wp1[c], qa[u], ap1);
            }
        }
        RED2(az0) RED2(az1) RED2(ar0) RED2(ar1)
        RED2(ap0) RED2(ap1) RED2(ax0) RED2(ax1)
        __syncthreads();
        if (l < 2) {
            const int j = 2 * g + l;
            const float aZ = (l == 0) ? az0 : az1, aR = (l == 0) ? ar0 : ar1;
            const float aP = (l == 0) ? ap0 : ap1, aX = (l == 0) ? ax0 : ax1;
            float zt = fsig(aZ + S->gz[j]);
            float rt = fsig(aR + S->gr[j]);
            float eta = ftanh(aX + rt * ftanh(aP + S->bh[j]));
            float hn = zt * S->hf[j] + (1.f - zt) * eta;
            S->hf[j] = hn;
            float ho = __shfl_xor(hn, 1);
            if (l == 0) S->hp[g] = pk(hn, ho);
        } else if (l == 2 && g < 32 && ts + 1 < TT) {
            const int c = g;
            const size_t base = ((size_t)b * TT + ts + 1) * INP;
            float a = (2 * c < INP) ? inp[base + 2 * c] : 0.f;
            float bv = (2 * c + 1 < INP) ? inp[base + 2 * c + 1] : 0.f;
            S->xp[p ^ 1][c] = pk(a, bv);
        } else if (l == 3 && g < 64 && ts + 1 < TT) {
            const int c = g;
            const size_t base = ((size_t)b * TT + ts + 1) * INP;
            S->xf[p ^ 1][c] = (c < INP) ? inp[base + c] : 0.f;
        }
        __syncthreads();
        // yhat partials: o = tid&63, seg s = tid>>6 covers h-pairs [16s,16s+16)
        {
            const int o = tid & 63, s = tid >> 6;
            float pp = 0;
#pragma unroll
            for (int c = 0; c < 16; ++c)
                pp = fd2(S->hp[s * 16 + c], S->cp[(s * 16 + c) * 64 + o], pp);
            S->part[s * 64 + o] = pp;
        }
        __syncthreads();
        if (tid < 64) {
            const int o = tid;
            float y = 0;
#pragma unroll
            for (int s2 = 0; s2 < 8; ++s2) y += S->part[s2 * 64 + o];
            if (o < INP) y += S->xf[p][o];
            else {
                float acc = 0;
                for (int d = 0; d < INP; ++d) acc += S->xf[p][d] * S->dp[d * 10 + (o - INP)];
                y += acc;
            }
            out[((size_t)b * TT + ts) * HUM + o] = y;
        }
    }
    if (tid < 256) out[OUT_HL + (size_t)b * 256 + tid] = S->hf[tid];
}

// ----------------------------------------------------------------- launch ---
extern "C" void kernel_launch(void* const* d_in, const int* in_sizes, int n_in,
                              void* d_out, int out_size, void* d_ws, size_t ws_size,
                              hipStream_t stream)
{
    const float* inputs = (const float*)d_in[0];
    const float* state  = (const float*)d_in[1];
    const float* eps    = (const float*)d_in[2];
    const float* eWih   = (const float*)d_in[3];
    const float* eWhh   = (const float*)d_in[4];
    const float* ebih   = (const float*)d_in[5];
    const float* ebhh   = (const float*)d_in[6];
    const float* to_mu  = (const float*)d_in[7];
    const float* to_ls  = (const float*)d_in[8];
    const float* W1     = (const float*)d_in[9];
    const float* b1     = (const float*)d_in[10];
    const float* W2     = (const float*)d_in[11];
    const float* b2     = (const float*)d_in[12];
    const float* W3     = (const float*)d_in[13];
    const float* b3     = (const float*)d_in[14];
    const float* gWih   = (const float*)d_in[15];
    const float* gWhh   = (const float*)d_in[16];
    const float* gbias  = (const float*)d_in[17];
    float* out = (float*)d_out;
    float* ws  = (float*)d_ws;

    float* henc = ws;            // 32768 floats
    float* psi2 = ws + 32768;    // 4096 floats
    float* psi  = ws + 36864;    // 128*96540 floats (~49.4 MB)

    (void)hipFuncSetAttribute((const void*)enc_kernel,
        hipFuncAttributeMaxDynamicSharedMemorySize, (int)sizeof(EncLds));
    (void)hipFuncSetAttribute((const void*)dec_kernel,
        hipFuncAttributeMaxDynamicSharedMemorySize, (int)sizeof(DecLds));

    enc_kernel<<<BB, 512, sizeof(EncLds), stream>>>(inputs, eWih, eWhh, ebih, ebhh, henc);
    latent_kernel<<<BB, 256, 0, stream>>>(henc, eps, to_mu, to_ls, W1, b1, W2, b2, psi2, out);
    psi3_kernel<<<(NPSI + 255) / 256, 256, 0, stream>>>(psi2, W3, b3, psi);
    dec_kernel<<<BB, 512, sizeof(DecLds), stream>>>(inputs, state, gWih, gWhh, gbias, psi, out);
}

// Round 3
// 5594.886 us; speedup vs baseline: 1.6767x; 1.6767x over previous
//
#include <hip/hip_runtime.h>

#define BB 128
#define TT 1024
#define INP 54
#define HUM 64
#define NPSI 96540
#define OFF_BH 65536
#define OFF_WIH 65792
#define OFF_C 79616
#define OFF_D 96000
#define OUT_MU 8388608
#define OUT_LS 8390656
#define OUT_HL 8392704

typedef unsigned int u32;
typedef unsigned short u16;
typedef _Float16 h2 __attribute__((ext_vector_type(2)));

__device__ __forceinline__ u32 pk(float a, float b) {
    h2 v; v.x = (_Float16)a; v.y = (_Float16)b;
    return __builtin_bit_cast(u32, v);
}
__device__ __forceinline__ float f16tof(u16 v) {
    return (float)__builtin_bit_cast(_Float16, v);
}
__device__ __forceinline__ u16 ftof16(float v) {
    return __builtin_bit_cast(u16, (_Float16)v);
}
__device__ __forceinline__ float fd2(u32 a, u32 b, float c) {
#if __has_builtin(__builtin_amdgcn_fdot2)
    return __builtin_amdgcn_fdot2(__builtin_bit_cast(h2, a), __builtin_bit_cast(h2, b), c, false);
#else
    h2 ha = __builtin_bit_cast(h2, a), hb = __builtin_bit_cast(h2, b);
    return c + (float)ha.x * (float)hb.x + (float)ha.y * (float)hb.y;
#endif
}
__device__ __forceinline__ float fsig(float x) { return 1.f / (1.f + __expf(-x)); }
__device__ __forceinline__ float ftanh(float x) { float e = __expf(2.f * x); return 1.f - 2.f / (e + 1.f); }

// quad reduction on the VALU pipe (DPP) — keeps the LDS pipe free
__device__ __forceinline__ float qred(float v) {
#if __has_builtin(__builtin_amdgcn_mov_dpp)
    int x = __builtin_bit_cast(int, v);
    v += __builtin_bit_cast(float, __builtin_amdgcn_mov_dpp(x, 0xB1, 0xF, 0xF, true)); // quad_perm [1,0,3,2]
    x = __builtin_bit_cast(int, v);
    v += __builtin_bit_cast(float, __builtin_amdgcn_mov_dpp(x, 0x4E, 0xF, 0xF, true)); // quad_perm [2,3,0,1]
    return v;
#else
    v += __shfl_xor(v, 1); v += __shfl_xor(v, 2);
    return v;
#endif
}

// ------------------------------------------------------- x-side projections --
// gout[(b*ct + tl)*768 + gr] = f16(dot(x[b, t0+tl, :], Wrow(gr)))
// mode0: all 768 rows from W0 (enc_Wih). mode1: rows<512 from W0 (gru_Wih),
// rows 512.. from psi16 Wih_p (f16).
__global__ __launch_bounds__(768) void gemm_x_kernel(
    const float* __restrict__ inp, const float* __restrict__ W0,
    const u16* __restrict__ psi16, int mode, int t0, int len, int ct, int nt,
    u16* __restrict__ gout)
{
    const int tid = threadIdx.x;
    const int b = blockIdx.x / nt, tc = blockIdx.x % nt;
    const int gr = tid;
    float w[INP];
    if (mode == 0 || gr < 512) {
        const float* wsrc = W0 + (size_t)gr * INP;
#pragma unroll
        for (int c = 0; c < INP; ++c) w[c] = wsrc[c];
    } else {
        const u16* wsrc = psi16 + (size_t)b * NPSI + OFF_WIH + (size_t)(gr - 512) * INP;
#pragma unroll
        for (int c = 0; c < INP; ++c) w[c] = f16tof(wsrc[c]);
    }
    const int tb = tc * 128;
    const int te = (tb + 128 < len) ? tb + 128 : len;
    for (int tl = tb; tl < te; ++tl) {
        const float* xr = inp + ((size_t)b * TT + t0 + tl) * INP;
        float a = 0.f;
#pragma unroll
        for (int c = 0; c < INP; ++c) a = __builtin_fmaf(xr[c], w[c], a);
        gout[((size_t)b * ct + tl) * 768 + gr] = ftof16(a);
    }
}

// ---------------------------------------------------------------- encoder ---
__global__ __launch_bounds__(1024) void enc_scan_kernel(
    const u16* __restrict__ gi, int t0, int len, int ct,
    const float* __restrict__ Whh, const float* __restrict__ bih,
    const float* __restrict__ bhh, float* __restrict__ hcarry)
{
    __shared__ __align__(16) u32 hpp[2][144];
    const int tid = threadIdx.x, b = blockIdx.x;
    const int l = tid & 3, j = tid >> 2;

    u32 wr[32], wz[32], wn[32];
    {
        const float* pr = Whh + (size_t)j * 256 + 64 * l;
        const float* pz = Whh + (size_t)(256 + j) * 256 + 64 * l;
        const float* pn = Whh + (size_t)(512 + j) * 256 + 64 * l;
#pragma unroll
        for (int c = 0; c < 32; ++c) {
            wr[c] = pk(pr[2 * c], pr[2 * c + 1]);
            wz[c] = pk(pz[2 * c], pz[2 * c + 1]);
            wn[c] = pk(pn[2 * c], pn[2 * c + 1]);
        }
    }
    const float brb = bih[j] + bhh[j];
    const float bzb = bih[256 + j] + bhh[256 + j];
    const float bib = bih[512 + j];
    const float bhb = bhh[512 + j];
    float hcur = 0.f;
    if (l == 0 && t0 > 0) hcur = hcarry[(size_t)b * 256 + j];
    if (tid < 128) {
        u32 hv = 0u;
        if (t0 > 0) hv = pk(hcarry[(size_t)b * 256 + 2 * tid], hcarry[(size_t)b * 256 + 2 * tid + 1]);
        hpp[0][36 * (tid >> 5) + (tid & 31)] = hv;
    }
    __syncthreads();

    const u16* gbase = gi + (size_t)b * ct * 768;
    float c0 = 0, c1 = 0, c2 = 0;
    if (l == 0) {
        c0 = f16tof(gbase[j]); c1 = f16tof(gbase[256 + j]); c2 = f16tof(gbase[512 + j]);
    }
    for (int tl = 0; tl < len; ++tl) {
        const int p = tl & 1;
        float n0 = 0, n1 = 0, n2 = 0;
        if (l == 0 && tl + 1 < len) {
            const u16* gn = gbase + (size_t)(tl + 1) * 768;
            n0 = f16tof(gn[j]); n1 = f16tof(gn[256 + j]); n2 = f16tof(gn[512 + j]);
        }
        float ar = 0, az = 0, ah = 0;
        const uint4* hq = (const uint4*)hpp[p];
#pragma unroll
        for (int cc = 0; cc < 8; ++cc) {
            uint4 q = hq[9 * l + cc];
            u32 qa[4] = {q.x, q.y, q.z, q.w};
#pragma unroll
            for (int u = 0; u < 4; ++u) {
                const int c = cc * 4 + u;
                ar = fd2(wr[c], qa[u], ar);
                az = fd2(wz[c], qa[u], az);
                ah = fd2(wn[c], qa[u], ah);
            }
        }
        ar = qred(ar); az = qred(az); ah = qred(ah);
        if (l == 0) {
            float r = fsig(ar + c0 + brb);
            float z = fsig(az + c1 + bzb);
            float nn = ftanh(c2 + bib + r * (ah + bhb));
            float hn = (1.f - z) * nn + z * hcur;
            hcur = hn;
            float ho = __shfl_xor(hn, 4);
            if ((j & 1) == 0) {
                int g = j >> 1;
                hpp[p ^ 1][36 * (g >> 5) + (g & 31)] = pk(hn, ho);
            }
        }
        c0 = n0; c1 = n1; c2 = n2;
        __syncthreads();
    }
    if (l == 0) hcarry[(size_t)b * 256 + j] = hcur;
}

// ----------------------------------------------------------------- latent ---
__global__ __launch_bounds__(256) void latent_kernel(
    const float* __restrict__ henc, const float* __restrict__ eps,
    const float* __restrict__ to_mu, const float* __restrict__ to_ls,
    const float* __restrict__ W1, const float* __restrict__ b1,
    const float* __restrict__ W2, const float* __restrict__ b2,
    float* __restrict__ psi2, float* __restrict__ out)
{
    __shared__ float h[256], zz[16], p1[256];
    const int tid = threadIdx.x, b = blockIdx.x;
    h[tid] = henc[(size_t)b * 256 + tid];
    __syncthreads();
    if (tid < 16) {
        float m = 0, s = 0;
        for (int k = 0; k < 256; ++k) {
            m += h[k] * to_mu[tid * 256 + k];
            s += h[k] * to_ls[tid * 256 + k];
        }
        out[OUT_MU + b * 16 + tid] = m;
        out[OUT_LS + b * 16 + tid] = s;
        zz[tid] = m + eps[b * 16 + tid] * __expf(s);
    }
    __syncthreads();
    {
        float a = b1[tid];
        for (int k = 0; k < 16; ++k) a += zz[k] * W1[tid * 16 + k];
        p1[tid] = ftanh(a);
    }
    __syncthreads();
    if (tid < 32) {
        float a = b2[tid];
        for (int k = 0; k < 256; ++k) a += p1[k] * W2[tid * 256 + k];
        psi2[b * 32 + tid] = a;
    }
}

// ------------------------------------------------------------------- psi3 ---
__global__ __launch_bounds__(256) void psi3_kernel(
    const float* __restrict__ psi2, const float* __restrict__ W3,
    const float* __restrict__ b3, u16* __restrict__ psi16)
{
    __shared__ float sp2[128 * 32];
    __shared__ float w3t[256 * 33];
    const int tid = threadIdx.x;
    const int n0 = blockIdx.x * 256;
    for (int idx = tid; idx < 4096; idx += 256) sp2[idx] = psi2[idx];
    for (int idx = tid; idx < 8192; idx += 256) {
        int row = idx >> 5, k = idx & 31;
        int n = n0 + row;
        w3t[row * 33 + k] = (n < NPSI) ? W3[(size_t)n * 32 + k] : 0.f;
    }
    __syncthreads();
    const int n = n0 + tid;
    if (n < NPSI) {
        float w[32];
#pragma unroll
        for (int k = 0; k < 32; ++k) w[k] = w3t[tid * 33 + k];
        const float bv = b3[n];
        for (int bi = 0; bi < 128; ++bi) {
            float a = bv;
#pragma unroll
            for (int k = 0; k < 32; ++k) a += sp2[bi * 32 + k] * w[k];
            psi16[(size_t)bi * NPSI + n] = ftof16(a);
        }
    }
}

// ------------------------------------------- decoder scan + fused C_p einsum -
__global__ __launch_bounds__(1024) void dec_scan_kernel(
    const u16* __restrict__ gx, int t0, int len, int ct,
    const float* __restrict__ state, const float* __restrict__ gWhh,
    const float* __restrict__ gbias, const u16* __restrict__ psi16,
    float* __restrict__ dcarry, float* __restrict__ out)
{
    __shared__ __align__(16) u32 hpp[2][144];
    __shared__ u32 cp[64 * 129];      // [o][pair q], stride 129 -> 2-way (free)
    __shared__ float part[16 * 64];
    const int tid = threadIdx.x, b = blockIdx.x;
    const int l = tid & 3, j = tid >> 2;
    const u16* pc = psi16 + (size_t)b * NPSI;

    u32 wz[32], wr[32], wp[32];
#pragma unroll
    for (int c = 0; c < 32; ++c) {
        const int h0 = 64 * l + 2 * c;
        wz[c] = pk(gWhh[(size_t)h0 * 512 + j], gWhh[(size_t)(h0 + 1) * 512 + j]);
        wr[c] = pk(gWhh[(size_t)h0 * 512 + 256 + j], gWhh[(size_t)(h0 + 1) * 512 + 256 + j]);
        wp[c] = (u32)pc[(size_t)h0 * 256 + j] | ((u32)pc[(size_t)(h0 + 1) * 256 + j] << 16);
    }
    const float gzb = gbias[j], grb = gbias[256 + j];
    const float bhb = f16tof(pc[OFF_BH + j]);
    // C_p -> LDS: cp[o*129 + q] packs columns o for h-pair q
    for (int idx = tid; idx < 8192; idx += 1024) {
        const int q = idx >> 6, o = idx & 63;
        cp[o * 129 + q] = (u32)pc[OFF_C + (size_t)(2 * q) * 64 + o]
                        | ((u32)pc[OFF_C + (size_t)(2 * q + 1) * 64 + o] << 16);
    }
    const float* hsrc = (t0 == 0) ? state : dcarry;
    float hcur = 0.f;
    if (l == 0) hcur = hsrc[(size_t)b * 256 + j];
    if (tid < 128) hpp[0][36 * (tid >> 5) + (tid & 31)] =
        pk(hsrc[(size_t)b * 256 + 2 * tid], hsrc[(size_t)b * 256 + 2 * tid + 1]);
    __syncthreads();

    const u16* gbase = gx + (size_t)b * ct * 768;
    const int o = tid & 63, s = tid >> 6;
    const int hqi = 36 * (s >> 2) + ((8 * s) & 31);   // hpp idx of pair 8s
    float c0 = 0, c1 = 0, c2 = 0;
    if (l == 0) {
        c0 = f16tof(gbase[j]); c1 = f16tof(gbase[256 + j]); c2 = f16tof(gbase[512 + j]);
    }
    for (int tl = 0; tl < len; ++tl) {
        const int p = tl & 1;
        float n0 = 0, n1 = 0, n2 = 0;
        if (l == 0 && tl + 1 < len) {
            const u16* gn = gbase + (size_t)(tl + 1) * 768;
            n0 = f16tof(gn[j]); n1 = f16tof(gn[256 + j]); n2 = f16tof(gn[512 + j]);
        }
        float az = 0, ar = 0, ap = 0;
        const uint4* hq = (const uint4*)hpp[p];
#pragma unroll
        for (int cc = 0; cc < 8; ++cc) {
            uint4 q = hq[9 * l + cc];
            u32 qa[4] = {q.x, q.y, q.z, q.w};
#pragma unroll
            for (int u = 0; u < 4; ++u) {
                const int c = cc * 4 + u;
                az = fd2(wz[c], qa[u], az);
                ar = fd2(wr[c], qa[u], ar);
                ap = fd2(wp[c], qa[u], ap);
            }
        }
        az = qred(az); ar = qred(ar); ap = qred(ap);
        if (l == 0) {
            float zt = fsig(az + c0 + gzb);
            float rt = fsig(ar + c1 + grb);
            float eta = ftanh(c2 + rt * ftanh(ap + bhb));
            float hn = zt * hcur + (1.f - zt) * eta;
            hcur = hn;
            float ho = __shfl_xor(hn, 4);
            if ((j & 1) == 0) {
                int g = j >> 1;
                hpp[p ^ 1][36 * (g >> 5) + (g & 31)] = pk(hn, ho);
            }
        }
        c0 = n0; c1 = n1; c2 = n2;
        __syncthreads();                       // A: h_t published
        {
            const uint4* h2q = (const uint4*)&hpp[p ^ 1][hqi];
            uint4 qa = h2q[0], qb = h2q[1];
            u32 hv[8] = {qa.x, qa.y, qa.z, qa.w, qb.x, qb.y, qb.z, qb.w};
            float acc = 0.f;
            const int cbase = o * 129 + s * 8;
#pragma unroll
            for (int i = 0; i < 8; ++i) acc = fd2(hv[i], cp[cbase + i], acc);
            part[s * 64 + o] = acc;
        }
        __syncthreads();                       // B: partials ready
        if (tid < 64) {
            float y = 0.f;
#pragma unroll
            for (int s2 = 0; s2 < 16; ++s2) y += part[s2 * 64 + tid];
            out[((size_t)b * TT + t0 + tl) * HUM + tid] = y;
        }
    }
    if (l == 0) {
        dcarry[(size_t)b * 256 + j] = hcur;
        if (t0 + len == TT) out[OUT_HL + (size_t)b * 256 + j] = hcur;
    }
}

// ------------------------------------------------- x add + D_p einsum fixup --
__global__ __launch_bounds__(256) void post_kernel(
    const float* __restrict__ inp, const u16* __restrict__ psi16,
    float* __restrict__ out)
{
    __shared__ float xs[128][55];
    __shared__ float ds[INP][10];
    const int tid = threadIdx.x;
    const int b = blockIdx.x >> 3, tile = blockIdx.x & 7;
    const int t0 = tile * 128;
    const u16* pc = psi16 + (size_t)b * NPSI;
    for (int idx = tid; idx < 540; idx += 256)
        ds[idx / 10][idx % 10] = f16tof(pc[OFF_D + idx]);
    for (int idx = tid; idx < 128 * INP; idx += 256) {
        const int t = idx / INP, d = idx % INP;
        xs[t][d] = inp[((size_t)b * TT + t0 + t) * INP + d];
    }
    __syncthreads();
    for (int i = 0; i < 32; ++i) {
        const int flat = i * 256 + tid;
        const int t = flat >> 6, o = flat & 63;
        const size_t oi = ((size_t)b * TT + t0 + t) * HUM + o;
        float y = out[oi];
        if (o < INP) y += xs[t][o];
        else {
            float acc = 0.f;
            for (int d = 0; d < INP; ++d) acc += xs[t][d] * ds[d][o - INP];
            y += acc;
        }
        out[oi] = y;
    }
}

// ----------------------------------------------------------------- launch ---
extern "C" void kernel_launch(void* const* d_in, const int* in_sizes, int n_in,
                              void* d_out, int out_size, void* d_ws, size_t ws_size,
                              hipStream_t stream)
{
    const float* inputs = (const float*)d_in[0];
    const float* state  = (const float*)d_in[1];
    const float* eps    = (const float*)d_in[2];
    const float* eWih   = (const float*)d_in[3];
    const float* eWhh   = (const float*)d_in[4];
    const float* ebih   = (const float*)d_in[5];
    const float* ebhh   = (const float*)d_in[6];
    const float* to_mu  = (const float*)d_in[7];
    const float* to_ls  = (const float*)d_in[8];
    const float* W1     = (const float*)d_in[9];
    const float* b1     = (const float*)d_in[10];
    const float* W2     = (const float*)d_in[11];
    const float* b2     = (const float*)d_in[12];
    const float* W3     = (const float*)d_in[13];
    const float* b3     = (const float*)d_in[14];
    const float* gWih   = (const float*)d_in[15];
    const float* gWhh   = (const float*)d_in[16];
    const float* gbias  = (const float*)d_in[17];
    float* out = (float*)d_out;
    float* ws  = (float*)d_ws;

    // ws layout (bytes): henc 131072 | psi2 16384 | dcarry 131072 |
    // psi16 24,714,240 | gbuf (chunk, adaptive)
    float* henc   = ws;
    float* psi2   = ws + 32768;
    float* dcarry = ws + 36864;
    u16*   psi16  = (u16*)(ws + 69632);
    u16*   gbuf   = (u16*)(ws + 6248192);
    const size_t used = (size_t)6248192 * 4;
    size_t avail = (ws_size > used + 4096) ? (ws_size - used - 4096) : 0;
    int ct = (int)(avail / ((size_t)BB * 768 * 2));
    if (ct > TT) ct = TT;
    if (ct < 1) ct = 1;

    for (int t0 = 0; t0 < TT; t0 += ct) {
        const int len = (TT - t0 < ct) ? (TT - t0) : ct;
        const int nt = (len + 127) / 128;
        gemm_x_kernel<<<BB * nt, 768, 0, stream>>>(inputs, eWih, psi16, 0, t0, len, ct, nt, gbuf);
        enc_scan_kernel<<<BB, 1024, 0, stream>>>(gbuf, t0, len, ct, eWhh, ebih, ebhh, henc);
    }
    latent_kernel<<<BB, 256, 0, stream>>>(henc, eps, to_mu, to_ls, W1, b1, W2, b2, psi2, out);
    psi3_kernel<<<(NPSI + 255) / 256, 256, 0, stream>>>(psi2, W3, b3, psi16);
    for (int t0 = 0; t0 < TT; t0 += ct) {
        const int len = (TT - t0 < ct) ? (TT - t0) : ct;
        const int nt = (len + 127) / 128;
        gemm_x_kernel<<<BB * nt, 768, 0, stream>>>(inputs, gWih, psi16, 1, t0, len, ct, nt, gbuf);
        dec_scan_kernel<<<BB, 1024, 0, stream>>>(gbuf, t0, len, ct, state, gWhh, gbias, psi16, dcarry, out);
    }
    post_kernel<<<BB * 8, 256, 0, stream>>>(inputs, psi16, out);
}